// Round 9
// baseline (19.325 us; speedup 1.0000x reference)
//
#include <hip/hip_runtime.h>

// Path signature depth 4, path (N=64, L=512, C=8) fp32. Two kernels.
//
// k1: 256 blocks = (batch n, g in 0..3), 4 waves. Wave w: 32-step chunk
//     signature fully in registers (lane (a,b) owns S4[a][b][*][*] as f2
//     pairs -> v_pk_fma_f32), with an explicit 2-stage software pipeline on
//     the LDS z-loads (step s+1 prefetched during step s compute — R8 was
//     latency-bound at 1 wave/SIMD). In-block 4-way combine -> partial -> ws.
// k2: 64 blocks; combines the 4 partials (3 products) -> out. Global b4
//     loads issued before LDS staging so their latency overlaps.
//
// R6 lesson: no atomic+__threadfence cross-block handoff (device-scope fence
// ~2us, serializes); kernel-launch boundary is the cheap device-wide barrier.
// R7 lesson: the pre-store __syncthreads IS required — L1/L2 store slices
// cross waves (threads 64..71 read L2 written by wave 0).
//
// LDS layouts for L123 (bank-conflict-free):
//   A-side (scalar access):  L1 [0,8), L2 [8,72), L3 at 72+(p*8+q)*9+r
//   B-side (float4 access):  L1/L2 flat,           L3 at 72+x*72+y*8+z
// L4 transposed layout: float4 #f of flat L4 (f = lane*16 + i) at T-index
// i*64 + lane (conflict-free LDS exchange, coalesced global ws).

typedef float f2 __attribute__((ext_vector_type(2)));

#define NB 64
#define LP 512
#define SIG 4680
#define O2 8
#define O3 72
#define O4 584
#define SB 648
#define L123_F4 146

#define A3IDX(pq, r) (72 + (pq) * 9 + (r))
#define B3IDX(x, y, z) (72 + (x) * 72 + (y) * 8 + (z))

__device__ __forceinline__ f2 mkf2(float x, float y) { f2 r; r[0] = x; r[1] = y; return r; }

// ---------------------------------------------------------------------------
// Chen product A <- A (x) B (element-parallel, 256 threads).
// a4: A's owned L4 elems (a,b,c=2w..2w+1,d) as 8 f2. Ap/Aq: A-layout L123
// ping-pong. B: B-layout L123. b4: B's owned L4 elems.
// ---------------------------------------------------------------------------
__device__ __forceinline__ void prod_core(
    f2 (&a4)[8], const f2 (&b4)[8],
    const float* Ap, float* Aq, const float* B,
    int tid, int w, int l, int a, int b)
{
    const int c0 = 2 * w;
    // level 4: A4[abcd] += B4 + A3[abc]B1[d] + A2[ab]B2[cd] + A1[a]B3[bcd]
    const float A1   = Ap[a];
    const float A2   = Ap[O2 + a * 8 + b];
    const float A3_0 = Ap[A3IDX(a * 8 + b, c0)];
    const float A3_1 = Ap[A3IDX(a * 8 + b, c0 + 1)];
    f2 b1p[4], b2p[8], b3p[8];
    *(float4*)&b1p[0] = *(const float4*)(B);
    *(float4*)&b1p[2] = *(const float4*)(B + 4);
    #pragma unroll
    for (int i = 0; i < 4; ++i) {
        *(float4*)&b2p[2 * i] = *(const float4*)(B + O2 + c0 * 8 + 4 * i);
        *(float4*)&b3p[2 * i] = *(const float4*)(B + B3IDX(b, c0, 0) + 4 * i);
    }
    #pragma unroll
    for (int cc = 0; cc < 2; ++cc) {
        const float A3c = cc ? A3_1 : A3_0;
        #pragma unroll
        for (int j = 0; j < 4; ++j)
            a4[cc * 4 + j] += b4[cc * 4 + j] + A3c * b1p[j]
                            + A2 * b2p[cc * 4 + j] + A1 * b3p[cc * 4 + j];
    }
    // level 3 (elements f0, f0+1): A3[pqr] += B3 + A2[pq]B1[r] + A1[p]B2[qr]
    const int f0 = 2 * tid;
    const int pp = f0 >> 6, qq = (f0 >> 3) & 7, rr = f0 & 7;
    const float A1p  = Ap[pp];
    const float A2pq = Ap[O2 + pp * 8 + qq];
    Aq[A3IDX(pp * 8 + qq, rr)]     = Ap[A3IDX(pp * 8 + qq, rr)]
        + B[B3IDX(pp, qq, rr)]     + A2pq * B[rr]     + A1p * B[O2 + qq * 8 + rr];
    Aq[A3IDX(pp * 8 + qq, rr + 1)] = Ap[A3IDX(pp * 8 + qq, rr + 1)]
        + B[B3IDX(pp, qq, rr + 1)] + A2pq * B[rr + 1] + A1p * B[O2 + qq * 8 + rr + 1];
    // level 2 / 1
    if (tid < 64) Aq[O2 + tid] = Ap[O2 + tid] + B[O2 + tid] + Ap[tid >> 3] * B[tid & 7];
    if (tid < 8)  Aq[tid] = Ap[tid] + B[tid];
}

// ---------------------------------------------------------------------------
// k1: 256 blocks x 256 thr. 32-step chunks + in-block 4-way combine.
// ---------------------------------------------------------------------------
__global__ __launch_bounds__(256) void k1_sig(const float* __restrict__ path,
                                              float* __restrict__ ws)
{
    __shared__ __align__(16) float zbuf[129 * 8];   // 128 rows + zero pad row
    __shared__ __align__(16) float sA[2][SB];
    __shared__ __align__(16) float sLb[3][SB];
    __shared__ __align__(16) float4 sT[4][1024];

    const int tid = threadIdx.x;
    const int n = blockIdx.x >> 2;
    const int g = blockIdx.x & 3;

    {   // stage 128 increments (zero-padded past t=510; exp(0) = identity)
        const int r = tid >> 1, h = tid & 1;
        const int t = g * 128 + r;
        const float4* p4 = (const float4*)path + (size_t)n * (LP * 2);
        float4 z4 = make_float4(0.f, 0.f, 0.f, 0.f);
        if (t < LP - 1) {
            float4 x0 = p4[t * 2 + h];
            float4 x1 = p4[t * 2 + 2 + h];
            z4 = make_float4(x1.x - x0.x, x1.y - x0.y, x1.z - x0.z, x1.w - x0.w);
        }
        ((float4*)zbuf)[tid] = z4;
        if (tid < 2) ((float4*)zbuf)[256 + tid] = make_float4(0.f, 0.f, 0.f, 0.f);
    }
    __syncthreads();

    const int w = tid >> 6, l = tid & 63;
    const int a = l >> 3, b = l & 7;
    const int f0 = 2 * tid;

    // ---- 32-step chunk signature in registers (packed f2 math),
    //      2-stage software pipeline on the z LDS loads ----
    float s1 = 0.f, s2 = 0.f;
    f2 s3p[4], s4p[32];
    #pragma unroll
    for (int i = 0; i < 4; ++i) s3p[i] = mkf2(0.f, 0.f);
    #pragma unroll
    for (int e = 0; e < 32; ++e) s4p[e] = mkf2(0.f, 0.f);

    const float* zw = zbuf + w * (32 * 8);
    float4 clo = *(const float4*)(zw);
    float4 chi = *(const float4*)(zw + 4);
    float zac = zw[a];
    float zbc = zw[b];

    #pragma unroll 4
    for (int s = 0; s < 32; ++s) {
        // prefetch step s+1 (row 128 is the zero pad for wave 3's last iter)
        const float* zn = zw + (s + 1) * 8;
        float4 nlo = *(const float4*)(zn);
        float4 nhi = *(const float4*)(zn + 4);
        float zan = zn[a];
        float zbn = zn[b];

        f2 zp[4];
        zp[0] = mkf2(clo.x, clo.y); zp[1] = mkf2(clo.z, clo.w);
        zp[2] = mkf2(chi.x, chi.y); zp[3] = mkf2(chi.z, chi.w);

        const float B4 = zbc * (zac * (1.f/24.f) + s1 * (1.f/6.f)) + s2 * 0.5f;
        const float G3 = zbc * (zac * (1.f/6.f)  + s1 * 0.5f)      + s2;
        f2 Acp[4];
        #pragma unroll
        for (int i = 0; i < 4; ++i) Acp[i] = B4 * zp[i] + s3p[i];
        #pragma unroll
        for (int c = 0; c < 8; ++c) {
            const float Ac = Acp[c >> 1][c & 1];
            #pragma unroll
            for (int j = 0; j < 4; ++j) s4p[c * 4 + j] += Ac * zp[j];
        }
        #pragma unroll
        for (int i = 0; i < 4; ++i) s3p[i] += G3 * zp[i];
        s2 += zbc * (zac * 0.5f + s1);
        s1 += zac;

        clo = nlo; chi = nhi; zac = zan; zbc = zbn;
    }

    // ---- publish: sig0 -> sA[0] (A-layout) + sT[0]; sig w>=1 -> sLb[w-1]
    //      (B-layout) + sT[w] ----
    if (w == 0) {
        if (b == 0) sA[0][a] = s1;
        sA[0][O2 + l] = s2;
        #pragma unroll
        for (int c = 0; c < 8; ++c) sA[0][A3IDX(l, c)] = s3p[c >> 1][c & 1];
    } else {
        float* SL = sLb[w - 1];
        if (b == 0) SL[a] = s1;
        SL[O2 + l] = s2;
        *(float4*)&SL[B3IDX(a, b, 0)] = make_float4(s3p[0][0], s3p[0][1], s3p[1][0], s3p[1][1]);
        *(float4*)&SL[B3IDX(a, b, 4)] = make_float4(s3p[2][0], s3p[2][1], s3p[3][0], s3p[3][1]);
    }
    #pragma unroll
    for (int i = 0; i < 16; ++i)
        sT[w][i * 64 + l] = make_float4(s4p[2*i][0], s4p[2*i][1], s4p[2*i+1][0], s4p[2*i+1][1]);
    __syncthreads();

    // ---- in-block combine: A = sig0 (x) sig1 (x) sig2 (x) sig3 ----
    f2 a4[8], b4[8];
    #pragma unroll
    for (int k = 0; k < 4; ++k) {
        float4 v = sT[0][(w * 4 + k) * 64 + l];
        a4[2*k] = mkf2(v.x, v.y); a4[2*k+1] = mkf2(v.z, v.w);
        float4 u = sT[1][(w * 4 + k) * 64 + l];
        b4[2*k] = mkf2(u.x, u.y); b4[2*k+1] = mkf2(u.z, u.w);
    }
    prod_core(a4, b4, sA[0], sA[1], sLb[0], tid, w, l, a, b);
    __syncthreads();
    #pragma unroll
    for (int k = 0; k < 4; ++k) {
        float4 u = sT[2][(w * 4 + k) * 64 + l];
        b4[2*k] = mkf2(u.x, u.y); b4[2*k+1] = mkf2(u.z, u.w);
    }
    prod_core(a4, b4, sA[1], sA[0], sLb[1], tid, w, l, a, b);
    __syncthreads();
    #pragma unroll
    for (int k = 0; k < 4; ++k) {
        float4 u = sT[3][(w * 4 + k) * 64 + l];
        b4[2*k] = mkf2(u.x, u.y); b4[2*k+1] = mkf2(u.z, u.w);
    }
    prod_core(a4, b4, sA[0], sA[1], sLb[2], tid, w, l, a, b);
    __syncthreads();    // REQUIRED: L1/L2 store below crosses waves (R7 bug)

    // ---- store partial (flat L123, T-layout L4) ----
    float* dst = ws + (size_t)blockIdx.x * SIG;
    if (tid < O3) dst[tid] = sA[1][tid];
    dst[O3 + f0]     = sA[1][A3IDX(f0 >> 3, f0 & 7)];
    dst[O3 + f0 + 1] = sA[1][A3IDX(f0 >> 3, (f0 & 7) + 1)];
    float4* dT = (float4*)(dst + O4);
    #pragma unroll
    for (int k = 0; k < 4; ++k)
        dT[(w * 4 + k) * 64 + l] = make_float4(a4[2*k][0], a4[2*k][1], a4[2*k+1][0], a4[2*k+1][1]);
}

// ---------------------------------------------------------------------------
// k2: 64 blocks x 256 thr; combine the 4 partials -> out (true flat layout).
// ---------------------------------------------------------------------------
__global__ __launch_bounds__(256) void k2_final(const float* __restrict__ ws,
                                                float* __restrict__ out)
{
    __shared__ __align__(16) float sA[2][SB];
    __shared__ __align__(16) float sLb[3][SB];

    const int tid = threadIdx.x;
    const int n = blockIdx.x;
    const int w = tid >> 6, l = tid & 63;
    const int a = l >> 3, b = l & 7;
    const int f0 = 2 * tid;
    const float* base = ws + (size_t)n * 4 * SIG;

    // own L4 loads FIRST (independent of LDS) so latency overlaps staging
    f2 a4[8], b4A[8], b4B[8], b4C[8];
    #pragma unroll
    for (int k = 0; k < 4; ++k) {
        const int ti = (w * 4 + k) * 64 + l;
        float4 v = ((const float4*)(base + O4))[ti];
        a4[2*k] = mkf2(v.x, v.y); a4[2*k+1] = mkf2(v.z, v.w);
        float4 u1 = ((const float4*)(base + SIG + O4))[ti];
        b4A[2*k] = mkf2(u1.x, u1.y); b4A[2*k+1] = mkf2(u1.z, u1.w);
        float4 u2 = ((const float4*)(base + 2 * SIG + O4))[ti];
        b4B[2*k] = mkf2(u2.x, u2.y); b4B[2*k+1] = mkf2(u2.z, u2.w);
        float4 u3 = ((const float4*)(base + 3 * SIG + O4))[ti];
        b4C[2*k] = mkf2(u3.x, u3.y); b4C[2*k+1] = mkf2(u3.z, u3.w);
    }

    // stage sig0 L123 -> sA[0] (A-layout)
    if (tid < O3) sA[0][tid] = base[tid];
    sA[0][A3IDX(f0 >> 3, f0 & 7)]       = base[O3 + f0];
    sA[0][A3IDX(f0 >> 3, (f0 & 7) + 1)] = base[O3 + f0 + 1];
    // stage sigs 1..3 L123 -> sLb (B-layout; f4-preserving remap)
    #pragma unroll
    for (int m = 1; m <= 3; ++m) {
        if (tid < L123_F4) {
            float4 v = ((const float4*)(base + (size_t)m * SIG))[tid];
            int d4;
            if (tid < 18) d4 = tid;
            else { const int j = tid - 18; d4 = 18 + (j >> 4) * 18 + (j & 15); }
            ((float4*)sLb[m - 1])[d4] = v;
        }
    }
    __syncthreads();

    prod_core(a4, b4A, sA[0], sA[1], sLb[0], tid, w, l, a, b);
    __syncthreads();
    prod_core(a4, b4B, sA[1], sA[0], sLb[1], tid, w, l, a, b);
    __syncthreads();
    prod_core(a4, b4C, sA[0], sA[1], sLb[2], tid, w, l, a, b);
    __syncthreads();    // REQUIRED: L1/L2 store below crosses waves (R7 bug)

    // store final signature (true flat layout)
    float* dst = out + (size_t)n * SIG;
    if (tid < O3) dst[tid] = sA[1][tid];
    dst[O3 + f0]     = sA[1][A3IDX(f0 >> 3, f0 & 7)];
    dst[O3 + f0 + 1] = sA[1][A3IDX(f0 >> 3, (f0 & 7) + 1)];
    float4* d4p = (float4*)(dst + O4);
    #pragma unroll
    for (int k = 0; k < 4; ++k)
        d4p[l * 16 + w * 4 + k] = make_float4(a4[2*k][0], a4[2*k][1], a4[2*k+1][0], a4[2*k+1][1]);
}

extern "C" void kernel_launch(void* const* d_in, const int* in_sizes, int n_in,
                              void* d_out, int out_size, void* d_ws, size_t ws_size,
                              hipStream_t stream) {
    const float* path = (const float*)d_in[0];
    float* out = (float*)d_out;
    float* ws  = (float*)d_ws;   // 256 * 4680 * 4 B = 4.79 MB used

    k1_sig<<<NB * 4, 256, 0, stream>>>(path, ws);
    k2_final<<<NB, 256, 0, stream>>>(ws, out);
}

// Round 10
// 18.341 us; speedup vs baseline: 1.0536x; 1.0536x over previous
//
#include <hip/hip_runtime.h>

// Path signature depth 4, path (N=64, L=512, C=8) fp32. Two kernels.
//
// k1: 256 blocks = (batch n, g in 0..3), 4 waves. Wave w: 32-step chunk
//     signature fully in registers (lane (a,b) owns S4[a][b][*][*] as f2
//     pairs -> v_pk_fma_f32). In-block 4-way combine (element-parallel Chen
//     products via LDS) -> partial sig (1/4 batch) -> ws.   [R8 form; R9's
//     explicit z-load pipeline was neutral->negative, reverted]
// k2: 256 blocks = (batch n, c-quadrant w4). Each block combines the 4
//     partials for ONE c-quadrant of L4 (1024 elems, 1 float4/thread/sig)
//     and redundantly computes the cheap L123 chain (identical bits in all
//     4 blocks; only w4==0 stores it). Fills all 256 CUs.
//
// R6 lesson: no atomic+__threadfence cross-block handoff (device-scope fence
// ~2us, serializes); kernel-launch boundary is the cheap device-wide barrier.
// R7 lesson: pre-store __syncthreads IS required — L1/L2 store slices cross
// waves.
//
// LDS layouts for L123 (bank-conflict-free):
//   A-side (scalar access):  L1 [0,8), L2 [8,72), L3 at 72+(p*8+q)*9+r
//   B-side (float4 access):  L1/L2 flat,           L3 at 72+x*72+y*8+z
// L4 transposed ws layout: float4 #(w*4+k)*64 + l holds elements
// (a=l>>3, b=l&7, c=2w+(k>>1), d=(k&1)*4 .. +3).

typedef float f2 __attribute__((ext_vector_type(2)));

#define NB 64
#define LP 512
#define SIG 4680
#define O2 8
#define O3 72
#define O4 584
#define SB 648
#define L123_F4 146

#define A3IDX(pq, r) (72 + (pq) * 9 + (r))
#define B3IDX(x, y, z) (72 + (x) * 72 + (y) * 8 + (z))

__device__ __forceinline__ f2 mkf2(float x, float y) { f2 r; r[0] = x; r[1] = y; return r; }

// ---------------------------------------------------------------------------
// Full Chen product A <- A (x) B (256 threads, 16 L4 elems/thread). Used in k1.
// ---------------------------------------------------------------------------
__device__ __forceinline__ void prod_core(
    f2 (&a4)[8], const f2 (&b4)[8],
    const float* Ap, float* Aq, const float* B,
    int tid, int w, int l, int a, int b)
{
    const int c0 = 2 * w;
    const float A1   = Ap[a];
    const float A2   = Ap[O2 + a * 8 + b];
    const float A3_0 = Ap[A3IDX(a * 8 + b, c0)];
    const float A3_1 = Ap[A3IDX(a * 8 + b, c0 + 1)];
    f2 b1p[4], b2p[8], b3p[8];
    *(float4*)&b1p[0] = *(const float4*)(B);
    *(float4*)&b1p[2] = *(const float4*)(B + 4);
    #pragma unroll
    for (int i = 0; i < 4; ++i) {
        *(float4*)&b2p[2 * i] = *(const float4*)(B + O2 + c0 * 8 + 4 * i);
        *(float4*)&b3p[2 * i] = *(const float4*)(B + B3IDX(b, c0, 0) + 4 * i);
    }
    #pragma unroll
    for (int cc = 0; cc < 2; ++cc) {
        const float A3c = cc ? A3_1 : A3_0;
        #pragma unroll
        for (int j = 0; j < 4; ++j)
            a4[cc * 4 + j] += b4[cc * 4 + j] + A3c * b1p[j]
                            + A2 * b2p[cc * 4 + j] + A1 * b3p[cc * 4 + j];
    }
    const int f0 = 2 * tid;
    const int pp = f0 >> 6, qq = (f0 >> 3) & 7, rr = f0 & 7;
    const float A1p  = Ap[pp];
    const float A2pq = Ap[O2 + pp * 8 + qq];
    Aq[A3IDX(pp * 8 + qq, rr)]     = Ap[A3IDX(pp * 8 + qq, rr)]
        + B[B3IDX(pp, qq, rr)]     + A2pq * B[rr]     + A1p * B[O2 + qq * 8 + rr];
    Aq[A3IDX(pp * 8 + qq, rr + 1)] = Ap[A3IDX(pp * 8 + qq, rr + 1)]
        + B[B3IDX(pp, qq, rr + 1)] + A2pq * B[rr + 1] + A1p * B[O2 + qq * 8 + rr + 1];
    if (tid < 64) Aq[O2 + tid] = Ap[O2 + tid] + B[O2 + tid] + Ap[tid >> 3] * B[tid & 7];
    if (tid < 8)  Aq[tid] = Ap[tid] + B[tid];
}

// ---------------------------------------------------------------------------
// Quadrant Chen product (k2): 4 L4 elems/thread (c fixed, d = dh..dh+3).
// ---------------------------------------------------------------------------
__device__ __forceinline__ void prod_core_q(
    f2 (&a4)[2], const f2 (&b4)[2],
    const float* Ap, float* Aq, const float* B,
    int tid, int a, int b, int c, int dh)
{
    const float A1  = Ap[a];
    const float A2  = Ap[O2 + a * 8 + b];
    const float A3c = Ap[A3IDX(a * 8 + b, c)];
    f2 b1p[2], b2p[2], b3p[2];
    *(float4*)&b1p[0] = *(const float4*)(B + dh);
    *(float4*)&b2p[0] = *(const float4*)(B + O2 + c * 8 + dh);
    *(float4*)&b3p[0] = *(const float4*)(B + B3IDX(b, c, dh));
    #pragma unroll
    for (int j = 0; j < 2; ++j)
        a4[j] += b4[j] + A3c * b1p[j] + A2 * b2p[j] + A1 * b3p[j];
    // L3 (2 elems), L2, L1 — identical in every quadrant block (redundant)
    const int f0 = 2 * tid;
    const int pp = f0 >> 6, qq = (f0 >> 3) & 7, rr = f0 & 7;
    const float A1p  = Ap[pp];
    const float A2pq = Ap[O2 + pp * 8 + qq];
    Aq[A3IDX(pp * 8 + qq, rr)]     = Ap[A3IDX(pp * 8 + qq, rr)]
        + B[B3IDX(pp, qq, rr)]     + A2pq * B[rr]     + A1p * B[O2 + qq * 8 + rr];
    Aq[A3IDX(pp * 8 + qq, rr + 1)] = Ap[A3IDX(pp * 8 + qq, rr + 1)]
        + B[B3IDX(pp, qq, rr + 1)] + A2pq * B[rr + 1] + A1p * B[O2 + qq * 8 + rr + 1];
    if (tid < 64) Aq[O2 + tid] = Ap[O2 + tid] + B[O2 + tid] + Ap[tid >> 3] * B[tid & 7];
    if (tid < 8)  Aq[tid] = Ap[tid] + B[tid];
}

// ---------------------------------------------------------------------------
// k1: 256 blocks x 256 thr. 32-step chunks + in-block 4-way combine. (R8)
// ---------------------------------------------------------------------------
__global__ __launch_bounds__(256) void k1_sig(const float* __restrict__ path,
                                              float* __restrict__ ws)
{
    __shared__ __align__(16) float zbuf[128 * 8];
    __shared__ __align__(16) float sA[2][SB];
    __shared__ __align__(16) float sLb[3][SB];
    __shared__ __align__(16) float4 sT[4][1024];

    const int tid = threadIdx.x;
    const int n = blockIdx.x >> 2;
    const int g = blockIdx.x & 3;

    {   // stage 128 increments (zero-padded past t=510; exp(0) = identity)
        const int r = tid >> 1, h = tid & 1;
        const int t = g * 128 + r;
        const float4* p4 = (const float4*)path + (size_t)n * (LP * 2);
        float4 z4 = make_float4(0.f, 0.f, 0.f, 0.f);
        if (t < LP - 1) {
            float4 x0 = p4[t * 2 + h];
            float4 x1 = p4[t * 2 + 2 + h];
            z4 = make_float4(x1.x - x0.x, x1.y - x0.y, x1.z - x0.z, x1.w - x0.w);
        }
        ((float4*)zbuf)[tid] = z4;
    }
    __syncthreads();

    const int w = tid >> 6, l = tid & 63;
    const int a = l >> 3, b = l & 7;
    const int f0 = 2 * tid;

    // ---- 32-step chunk signature in registers (packed f2 math) ----
    float s1 = 0.f, s2 = 0.f;
    f2 s3p[4], s4p[32];
    #pragma unroll
    for (int i = 0; i < 4; ++i) s3p[i] = mkf2(0.f, 0.f);
    #pragma unroll
    for (int e = 0; e < 32; ++e) s4p[e] = mkf2(0.f, 0.f);

    const float* zw = zbuf + w * (32 * 8);
    #pragma unroll 4
    for (int s = 0; s < 32; ++s) {
        const float* zs = zw + s * 8;
        f2 zp[4];
        #pragma unroll
        for (int j = 0; j < 4; ++j) zp[j] = ((const f2*)zs)[j];
        const float za  = zs[a];
        const float zbv = zs[b];
        const float B4 = zbv * (za * (1.f/24.f) + s1 * (1.f/6.f)) + s2 * 0.5f;
        const float G3 = zbv * (za * (1.f/6.f)  + s1 * 0.5f)      + s2;
        f2 Acp[4];
        #pragma unroll
        for (int i = 0; i < 4; ++i) Acp[i] = B4 * zp[i] + s3p[i];
        #pragma unroll
        for (int c = 0; c < 8; ++c) {
            const float Ac = Acp[c >> 1][c & 1];
            #pragma unroll
            for (int j = 0; j < 4; ++j) s4p[c * 4 + j] += Ac * zp[j];
        }
        #pragma unroll
        for (int i = 0; i < 4; ++i) s3p[i] += G3 * zp[i];
        s2 += zbv * (za * 0.5f + s1);
        s1 += za;
    }

    // ---- publish ----
    if (w == 0) {
        if (b == 0) sA[0][a] = s1;
        sA[0][O2 + l] = s2;
        #pragma unroll
        for (int c = 0; c < 8; ++c) sA[0][A3IDX(l, c)] = s3p[c >> 1][c & 1];
    } else {
        float* SL = sLb[w - 1];
        if (b == 0) SL[a] = s1;
        SL[O2 + l] = s2;
        *(float4*)&SL[B3IDX(a, b, 0)] = make_float4(s3p[0][0], s3p[0][1], s3p[1][0], s3p[1][1]);
        *(float4*)&SL[B3IDX(a, b, 4)] = make_float4(s3p[2][0], s3p[2][1], s3p[3][0], s3p[3][1]);
    }
    #pragma unroll
    for (int i = 0; i < 16; ++i)
        sT[w][i * 64 + l] = make_float4(s4p[2*i][0], s4p[2*i][1], s4p[2*i+1][0], s4p[2*i+1][1]);
    __syncthreads();

    // ---- in-block combine: A = sig0 (x) sig1 (x) sig2 (x) sig3 ----
    f2 a4[8], b4[8];
    #pragma unroll
    for (int k = 0; k < 4; ++k) {
        float4 v = sT[0][(w * 4 + k) * 64 + l];
        a4[2*k] = mkf2(v.x, v.y); a4[2*k+1] = mkf2(v.z, v.w);
        float4 u = sT[1][(w * 4 + k) * 64 + l];
        b4[2*k] = mkf2(u.x, u.y); b4[2*k+1] = mkf2(u.z, u.w);
    }
    prod_core(a4, b4, sA[0], sA[1], sLb[0], tid, w, l, a, b);
    __syncthreads();
    #pragma unroll
    for (int k = 0; k < 4; ++k) {
        float4 u = sT[2][(w * 4 + k) * 64 + l];
        b4[2*k] = mkf2(u.x, u.y); b4[2*k+1] = mkf2(u.z, u.w);
    }
    prod_core(a4, b4, sA[1], sA[0], sLb[1], tid, w, l, a, b);
    __syncthreads();
    #pragma unroll
    for (int k = 0; k < 4; ++k) {
        float4 u = sT[3][(w * 4 + k) * 64 + l];
        b4[2*k] = mkf2(u.x, u.y); b4[2*k+1] = mkf2(u.z, u.w);
    }
    prod_core(a4, b4, sA[0], sA[1], sLb[2], tid, w, l, a, b);
    __syncthreads();    // REQUIRED: L1/L2 store below crosses waves (R7 bug)

    // ---- store partial (flat L123, T-layout L4) ----
    float* dst = ws + (size_t)blockIdx.x * SIG;
    if (tid < O3) dst[tid] = sA[1][tid];
    dst[O3 + f0]     = sA[1][A3IDX(f0 >> 3, f0 & 7)];
    dst[O3 + f0 + 1] = sA[1][A3IDX(f0 >> 3, (f0 & 7) + 1)];
    float4* dT = (float4*)(dst + O4);
    #pragma unroll
    for (int k = 0; k < 4; ++k)
        dT[(w * 4 + k) * 64 + l] = make_float4(a4[2*k][0], a4[2*k][1], a4[2*k+1][0], a4[2*k+1][1]);
}

// ---------------------------------------------------------------------------
// k2: 256 blocks x 256 thr = (batch n, c-quadrant w4). Combine 4 partials.
// ---------------------------------------------------------------------------
__global__ __launch_bounds__(256) void k2_final(const float* __restrict__ ws,
                                                float* __restrict__ out)
{
    __shared__ __align__(16) float sA[2][SB];
    __shared__ __align__(16) float sLb[3][SB];

    const int tid = threadIdx.x;
    const int n  = blockIdx.x >> 2;
    const int w4 = blockIdx.x & 3;
    const int a = tid >> 5, b = (tid >> 2) & 7, q = tid & 3;
    const int cc = q >> 1, dh4 = q & 1;
    const int c  = 2 * w4 + cc;
    const int dh = dh4 * 4;
    const int f0 = 2 * tid;
    const float* base = ws + (size_t)n * 4 * SIG;

    // own L4 quadrant slice: 1 float4 per sig (T-layout index)
    const int ti = (w4 * 4 + cc * 2 + dh4) * 64 + (a * 8 + b);
    f2 a4[2], b4A[2], b4B[2], b4C[2];
    {
        float4 v  = ((const float4*)(base + O4))[ti];
        a4[0] = mkf2(v.x, v.y);  a4[1] = mkf2(v.z, v.w);
        float4 u1 = ((const float4*)(base + SIG + O4))[ti];
        b4A[0] = mkf2(u1.x, u1.y); b4A[1] = mkf2(u1.z, u1.w);
        float4 u2 = ((const float4*)(base + 2 * SIG + O4))[ti];
        b4B[0] = mkf2(u2.x, u2.y); b4B[1] = mkf2(u2.z, u2.w);
        float4 u3 = ((const float4*)(base + 3 * SIG + O4))[ti];
        b4C[0] = mkf2(u3.x, u3.y); b4C[1] = mkf2(u3.z, u3.w);
    }

    // stage sig0 L123 -> sA[0] (A-layout)
    if (tid < O3) sA[0][tid] = base[tid];
    sA[0][A3IDX(f0 >> 3, f0 & 7)]       = base[O3 + f0];
    sA[0][A3IDX(f0 >> 3, (f0 & 7) + 1)] = base[O3 + f0 + 1];
    // stage sigs 1..3 L123 -> sLb (B-layout; f4-preserving remap)
    #pragma unroll
    for (int m = 1; m <= 3; ++m) {
        if (tid < L123_F4) {
            float4 v = ((const float4*)(base + (size_t)m * SIG))[tid];
            int d4;
            if (tid < 18) d4 = tid;
            else { const int j = tid - 18; d4 = 18 + (j >> 4) * 18 + (j & 15); }
            ((float4*)sLb[m - 1])[d4] = v;
        }
    }
    __syncthreads();

    prod_core_q(a4, b4A, sA[0], sA[1], sLb[0], tid, a, b, c, dh);
    __syncthreads();
    prod_core_q(a4, b4B, sA[1], sA[0], sLb[1], tid, a, b, c, dh);
    __syncthreads();
    prod_core_q(a4, b4C, sA[0], sA[1], sLb[2], tid, a, b, c, dh);
    __syncthreads();    // REQUIRED: L1/L2 store below crosses waves (R7 bug)

    // store final signature (true flat layout)
    float* dst = out + (size_t)n * SIG;
    if (w4 == 0) {   // L123 identical in all 4 quadrant blocks; store once
        if (tid < O3) dst[tid] = sA[1][tid];
        dst[O3 + f0]     = sA[1][A3IDX(f0 >> 3, f0 & 7)];
        dst[O3 + f0 + 1] = sA[1][A3IDX(f0 >> 3, (f0 & 7) + 1)];
    }
    float4* d4p = (float4*)(dst + O4);
    d4p[((a * 8 + b) * 8 + c) * 2 + dh4] =
        make_float4(a4[0][0], a4[0][1], a4[1][0], a4[1][1]);
}

extern "C" void kernel_launch(void* const* d_in, const int* in_sizes, int n_in,
                              void* d_out, int out_size, void* d_ws, size_t ws_size,
                              hipStream_t stream) {
    const float* path = (const float*)d_in[0];
    float* out = (float*)d_out;
    float* ws  = (float*)d_ws;   // 256 * 4680 * 4 B = 4.79 MB used

    k1_sig<<<NB * 4, 256, 0, stream>>>(path, ws);
    k2_final<<<NB * 4, 256, 0, stream>>>(ws, out);
}